// Round 10
// baseline (75.089 us; speedup 1.0000x reference)
//
#include <hip/hip_runtime.h>
#include <math.h>
#include <float.h>

#define MAX_DET 25
#define IOU_THRES 0.7f
#define MAX_WH 7680.0f
#define TOPK 256
#define MCAP 512

__device__ __forceinline__ float sigm(float v) {
#pragma clang fp contract(off)
    return 1.0f / (1.0f + expf(-v));
}

// ---------------- Slim decode: conf + argmax class only (2 lanes/candidate) ----------------
__global__ __launch_bounds__(256) void decode_all_kernel(
    const float* __restrict__ x0, const float* __restrict__ x1, const float* __restrict__ x2,
    float* __restrict__ confW, unsigned short* __restrict__ bcW)
{
#pragma clang fp contract(off)
    int t = blockIdx.x * 256 + threadIdx.x;
    int g = t >> 1;          // global candidate id, [0, 403200)
    int l2 = t & 1;
    const float* row;
    if (g < 307200)       row = x0 + (long)g * 85;
    else if (g < 384000)  row = x1 + (long)(g - 307200) * 85;
    else                  row = x2 + (long)(g - 384000) * 85;

    // max over 80 class logits; lane l2 owns classes {l2, l2+2, ...} ascending
    float bv = -FLT_MAX; int bc = 0;
#pragma unroll
    for (int j = 0; j < 40; ++j) {
        float v = row[5 + l2 + 2 * j];
        if (v > bv) { bv = v; bc = l2 + 2 * j; }
    }
    {
        float ov = __shfl_xor(bv, 1);
        int   oc = __shfl_xor(bc, 1);
        if (ov > bv || (ov == bv && oc < bc)) { bv = ov; bc = oc; }
    }
    if (l2 != 0) return;

    float v4 = row[4];
    confW[g] = sigm(bv) * sigm(v4);
    bcW[g] = (unsigned short)bc;
}

// ---------------- Fused per-group: radix-select + box recompute + NMS + gather ----------------
struct LvlParams {
    const float* feat;
    const float* x;      // level x base
    long candOff;        // candidate offset of level in confW/bcW
    long outOff;         // float offset of level in d_out
    int C;
};

template<int NY, int NX>
__device__ __forceinline__ void run_group(
    const float* __restrict__ gconf, const unsigned short* __restrict__ gbc,
    const float* __restrict__ xg, const float* __restrict__ anch,
    const float* __restrict__ feat, int C, long outOff, int b,
    float* sconf, unsigned long long* sk, unsigned* hists, float (*sbox)[4],
    int* selIdx, int* selValid, unsigned* wtot /*16*/, unsigned* misc /*4*/,
    float* __restrict__ out)
{
#pragma clang fp contract(off)
    constexpr int HW = NY * NX;
    constexpr int NPC = 3 * HW;
    const int tid = threadIdx.x;
    const int lane = tid & 63;
    const int wid = tid >> 6;

    if (tid < MAX_DET) selValid[tid] = 0;
    if (tid == 0) misc[0] = 0;
    for (int i = tid; i < 4096; i += 1024) hists[i] = 0;
    __syncthreads();

    // ---- stage conf in LDS + pass-0 histogram fused (2 sub-hists) ----
    const float4* gc4 = (const float4*)gconf;
    float4* sc4 = (float4*)sconf;
    const int sh = (tid & 1) << 11;
    for (int i = tid; i < NPC / 4; i += 1024) {
        float4 v = gc4[i];
        sc4[i] = v;
        atomicAdd(&hists[sh + (__float_as_uint(v.x) >> 19)], 1u);
        atomicAdd(&hists[sh + (__float_as_uint(v.y) >> 19)], 1u);
        atomicAdd(&hists[sh + (__float_as_uint(v.z) >> 19)], 1u);
        atomicAdd(&hists[sh + (__float_as_uint(v.w) >> 19)], 1u);
    }
    __syncthreads();

    // ---- exact top-TOPK threshold via 2-pass radix histogram ----
    unsigned B = 0, B2 = 0, K2 = 0;
    for (int pass = 0; pass < 2; ++pass) {
        if (pass == 1) {
            // zero + rebuild histogram on refinement bits for bin B
            __syncthreads();
            for (int i = tid; i < 4096; i += 1024) hists[i] = 0;
            __syncthreads();
            for (int i = tid; i < NPC; i += 1024) {
                unsigned bits = __float_as_uint(sconf[i]);
                if ((bits >> 19) == B)
                    atomicAdd(&hists[sh + ((bits >> 8) & 2047u)], 1u);
            }
            __syncthreads();
        }
        unsigned part = hists[2 * tid] + hists[2 * tid + 1]
                      + hists[2048 + 2 * tid] + hists[2048 + 2 * tid + 1];
        unsigned s = part;
#pragma unroll
        for (int d = 1; d < 64; d <<= 1) {
            unsigned v = __shfl_down(s, d);
            if (lane < 64 - d) s += v;
        }
        if (lane == 0) wtot[wid] = s;
        __syncthreads();
        unsigned S = s;
        for (int w = wid + 1; w < 16; ++w) S += wtot[w];
        unsigned Ktgt = (pass == 0) ? TOPK : K2;
        if (S >= Ktgt && S - part < Ktgt) {     // unique crossing thread
            unsigned acc = S - part;
            for (int i = 1; i >= 0; --i) {
                int bin = 2 * tid + i;
                unsigned h = hists[bin] + hists[2048 + bin];
                acc += h;
                if (acc >= Ktgt) { misc[2] = (unsigned)bin; misc[3] = acc - h; break; }
            }
        }
        __syncthreads();
        if (pass == 0) { B = misc[2]; K2 = Ktgt - misc[3]; }
        else           { B2 = misc[2]; }
    }
    unsigned T = (B << 19) | (B2 << 8);

    // ---- collect {bits >= T} into LDS key list ----
    for (int i = tid; i < NPC; i += 1024) {
        unsigned bits = __float_as_uint(sconf[i]);
        if (bits >= T) {
            unsigned pos = atomicAdd(&misc[0], 1u);
            if (pos < MCAP)
                sk[pos] = ((unsigned long long)bits << 32) | (unsigned)(~i);
        }
    }
    __syncthreads();
    unsigned cn = misc[0];
    int n = (cn < (unsigned)MCAP) ? (int)cn : MCAP;

    // ---- recompute boxes for collected candidates (bit-identical arithmetic) ----
    for (int i = tid; i < n; i += 1024) {
        int idx = (int)(~(unsigned)sk[i]);
        const float* row = xg + (long)idx * 85;
        float v0 = row[0], v1 = row[1], v2 = row[2], v3 = row[3];
        int bc = (int)gbc[idx];
        int a   = idx / HW;
        int rem = idx - a * HW;
        int gy  = rem / NX;
        int gx  = rem - gy * NX;

        float cx = sigm(v0) * 2.0f + ((float)gx - 0.5f);
        float cy = sigm(v1) * 2.0f + ((float)gy - 0.5f);
        float tw = sigm(v2) * 2.0f, th = sigm(v3) * 2.0f;
        float w = (tw * tw) * anch[a * 2 + 0];
        float h = (th * th) * anch[a * 2 + 1];
        float x1 = cx - w / 2.0f, y1 = cy - h / 2.0f;
        float x2 = cx + w / 2.0f, y2 = cy + h / 2.0f;
        float offc = (float)bc * MAX_WH;
        sbox[i][0] = x1 + offc; sbox[i][1] = y1 + offc;
        sbox[i][2] = x2 + offc; sbox[i][3] = y2 + offc;
    }
    __syncthreads();

    // ---- wave-0 register-resident selection-sort NMS (no block barriers) ----
    if (tid < 64) {
        unsigned long long kreg[8];
#pragma unroll
        for (int j = 0; j < 8; ++j) {
            int s = tid + 64 * j;
            kreg[j] = (s < n) ? sk[s] : 0ULL;
        }
        float ex1 = 0.f, ey1 = 0.f, ex2 = 0.f, ey2 = 0.f;  // lane t holds selected box t
        int k = 0;
        while (k < MAX_DET) {
            unsigned long long mk = kreg[0]; int ms = tid;
#pragma unroll
            for (int j = 1; j < 8; ++j)
                if (kreg[j] > mk) { mk = kreg[j]; ms = tid + 64 * j; }
#pragma unroll
            for (int off = 32; off; off >>= 1) {
                unsigned long long ok = __shfl_xor(mk, off);
                int os = __shfl_xor(ms, off);
                if (ok > mk) { mk = ok; ms = os; }
            }
            if (mk == 0ULL) break;          // exhausted
#pragma unroll
            for (int j = 0; j < 8; ++j)
                if (ms == tid + 64 * j) kreg[j] = 0ULL;

            float cx1 = sbox[ms][0], cy1 = sbox[ms][1];
            float cx2 = sbox[ms][2], cy2 = sbox[ms][3];
            bool rej = false;
            if (tid < k) {
                float ltx = fmaxf(ex1, cx1), lty = fmaxf(ey1, cy1);
                float rbx = fminf(ex2, cx2), rby = fminf(ey2, cy2);
                float ww = fmaxf(rbx - ltx, 0.0f), hh = fmaxf(rby - lty, 0.0f);
                float inter = ww * hh;
                float area1 = (ex2 - ex1) * (ey2 - ey1);
                float area2 = (cx2 - cx1) * (cy2 - cy1);
                float iou = inter / (area1 + area2 - inter);
                rej = iou > IOU_THRES;
            }
            rej = __any(rej);
            if (!rej) {
                if (tid == k) { ex1 = cx1; ey1 = cy1; ex2 = cx2; ey2 = cy2; }
                if (tid == 0) { selIdx[k] = (int)(~(unsigned)mk); selValid[k] = 1; }
                ++k;
            }
        }
    }
    __syncthreads();

    // ---- fused gather: parallel over 25*C output elements ----
    const float* fb = feat + (long)b * C * HW;
    long obase = outOff + (long)b * MAX_DET * C;
    for (int e = tid; e < MAX_DET * C; e += 1024) {
        int k2 = e / C, c = e - k2 * C;
        float val = 0.0f;
        if (selValid[k2]) {
            int idx = selIdx[k2];
            int rem = idx % HW;
            val = fb[(long)c * HW + rem];   // rem = gy*NX + gx
        }
        out[obase + e] = val;
    }
}

__global__ __launch_bounds__(1024) void select_nms_gather_kernel(
    const float* __restrict__ confW, const unsigned short* __restrict__ bcW,
    const float* __restrict__ anch, float* __restrict__ out,
    LvlParams p0, LvlParams p1, LvlParams p2)
{
    __shared__ float sconf[19200];
    __shared__ unsigned long long sk[MCAP];
    __shared__ unsigned hists[4096];
    __shared__ float sbox[MCAP][4];
    __shared__ int   selIdx[MAX_DET];
    __shared__ int   selValid[MAX_DET];
    __shared__ unsigned wtot[16];
    __shared__ unsigned misc[4];

    int grp = blockIdx.x;
    int lvl = grp >> 4, b = grp & 15;
    if (lvl == 0) {
        long base = p0.candOff + (long)b * 19200;
        run_group<80, 80>(confW + base, bcW + base, p0.x + base * 85, anch + 0,
                          p0.feat, p0.C, p0.outOff, b,
                          sconf, sk, hists, sbox, selIdx, selValid, wtot, misc, out);
    } else if (lvl == 1) {
        long base = p1.candOff + (long)b * 4800;
        run_group<40, 40>(confW + base, bcW + base, p1.x + (long)b * 4800 * 85, anch + 6,
                          p1.feat, p1.C, p1.outOff, b,
                          sconf, sk, hists, sbox, selIdx, selValid, wtot, misc, out);
    } else {
        long base = p2.candOff + (long)b * 1200;
        run_group<20, 20>(confW + base, bcW + base, p2.x + (long)b * 1200 * 85, anch + 12,
                          p2.feat, p2.C, p2.outOff, b,
                          sconf, sk, hists, sbox, selIdx, selValid, wtot, misc, out);
    }
}

extern "C" void kernel_launch(void* const* d_in, const int* in_sizes, int n_in,
                              void* d_out, int out_size, void* d_ws, size_t ws_size,
                              hipStream_t stream)
{
    const float* xs[3] = {nullptr, nullptr, nullptr};
    const float* fs[3] = {nullptr, nullptr, nullptr};
    const float* anch  = nullptr;
    for (int i = 0; i < n_in; ++i) {
        const float* p = (const float*)d_in[i];
        switch (in_sizes[i]) {
            case 26112000: xs[0] = p; break;
            case 6528000:  xs[1] = p; break;
            case 1632000:  xs[2] = p; break;
            case 13107200: fs[0] = p; break;
            case 6553600:  fs[1] = p; break;
            case 3276800:  fs[2] = p; break;
            case 18:       anch  = p; break;
        }
    }

    char* wsb = (char*)d_ws;
    float*          confW = (float*)wsb;                       // 403200 f32
    unsigned short* bcW   = (unsigned short*)(wsb + 1612800L); // 403200 u16

    decode_all_kernel<<<3150, 256, 0, stream>>>(xs[0], xs[1], xs[2], confW, bcW);

    LvlParams P0{fs[0], xs[0], 0L,      0L,      128};
    LvlParams P1{fs[1], xs[1], 307200L, 51200L,  256};
    LvlParams P2{fs[2], xs[2], 384000L, 153600L, 512};

    select_nms_gather_kernel<<<48, 1024, 0, stream>>>(confW, bcW, anch, (float*)d_out, P0, P1, P2);
}

// Round 11
// 60.881 us; speedup vs baseline: 1.2334x; 1.2334x over previous
//
#include <hip/hip_runtime.h>
#include <math.h>
#include <float.h>

#define MAX_DET 25
#define IOU_THRES 0.7f
#define MAX_WH 7680.0f
#define TOPK 256
#define MCAP 512

__device__ __forceinline__ float sigm(float v) {
#pragma clang fp contract(off)
    return 1.0f / (1.0f + expf(-v));
}

// ---------------- Slim decode: conf + argmax class only (4 lanes/candidate) ----------------
// All 20 class loads batched into registers (static indices) -> 20 outstanding
// loads per lane before the first consumer; one s_waitcnt instead of several.
__global__ __launch_bounds__(256) void decode_all_kernel(
    const float* __restrict__ x0, const float* __restrict__ x1, const float* __restrict__ x2,
    float* __restrict__ confW, unsigned short* __restrict__ bcW)
{
#pragma clang fp contract(off)
    int t = blockIdx.x * 256 + threadIdx.x;
    int g = t >> 2;          // global candidate id, [0, 403200)
    int l4 = t & 3;
    const float* row;
    if (g < 307200)       row = x0 + (long)g * 85;
    else if (g < 384000)  row = x1 + (long)(g - 307200) * 85;
    else                  row = x2 + (long)(g - 384000) * 85;

    // batch-load the 20 class logits this lane owns (classes {l4, l4+4, ...})
    float cv[20];
#pragma unroll
    for (int j = 0; j < 20; ++j) cv[j] = row[5 + l4 + 4 * j];
    float v4 = row[4];       // obj logit (same cache line region, issued with the batch)

    float bv = -FLT_MAX; int bc = 0;
#pragma unroll
    for (int j = 0; j < 20; ++j) {
        if (cv[j] > bv) { bv = cv[j]; bc = l4 + 4 * j; }
    }
#pragma unroll
    for (int off = 2; off; off >>= 1) {
        float ov = __shfl_xor(bv, off);
        int   oc = __shfl_xor(bc, off);
        if (ov > bv || (ov == bv && oc < bc)) { bv = ov; bc = oc; }
    }
    if (l4 != 0) return;

    confW[g] = sigm(bv) * sigm(v4);
    bcW[g] = (unsigned short)bc;
}

// ---------------- Fused per-group: radix-select + box recompute + NMS + gather ----------------
struct LvlParams {
    const float* feat;
    const float* x;      // level x base
    long candOff;        // candidate offset of level in confW/bcW
    long outOff;         // float offset of level in d_out
    int C;
};

template<int NY, int NX>
__device__ __forceinline__ void run_group(
    const float* __restrict__ gconf, const unsigned short* __restrict__ gbc,
    const float* __restrict__ xg, const float* __restrict__ anch,
    const float* __restrict__ feat, int C, long outOff, int b,
    float* sconf, unsigned long long* sk, unsigned* hists, float (*sbox)[4],
    int* selIdx, int* selValid, unsigned* wtot /*16*/, unsigned* misc /*4*/,
    float* __restrict__ out)
{
#pragma clang fp contract(off)
    constexpr int HW = NY * NX;
    constexpr int NPC = 3 * HW;
    const int tid = threadIdx.x;
    const int lane = tid & 63;
    const int wid = tid >> 6;

    if (tid < MAX_DET) selValid[tid] = 0;
    if (tid == 0) misc[0] = 0;
    for (int i = tid; i < 4096; i += 1024) hists[i] = 0;
    __syncthreads();

    // ---- stage conf in LDS + pass-0 histogram fused (2 sub-hists) ----
    const float4* gc4 = (const float4*)gconf;
    float4* sc4 = (float4*)sconf;
    const int sh = (tid & 1) << 11;
    for (int i = tid; i < NPC / 4; i += 1024) {
        float4 v = gc4[i];
        sc4[i] = v;
        atomicAdd(&hists[sh + (__float_as_uint(v.x) >> 19)], 1u);
        atomicAdd(&hists[sh + (__float_as_uint(v.y) >> 19)], 1u);
        atomicAdd(&hists[sh + (__float_as_uint(v.z) >> 19)], 1u);
        atomicAdd(&hists[sh + (__float_as_uint(v.w) >> 19)], 1u);
    }
    __syncthreads();

    // ---- exact top-TOPK threshold via 2-pass radix histogram ----
    unsigned B = 0, B2 = 0, K2 = 0;
    for (int pass = 0; pass < 2; ++pass) {
        if (pass == 1) {
            __syncthreads();
            for (int i = tid; i < 4096; i += 1024) hists[i] = 0;
            __syncthreads();
            for (int i = tid; i < NPC; i += 1024) {
                unsigned bits = __float_as_uint(sconf[i]);
                if ((bits >> 19) == B)
                    atomicAdd(&hists[sh + ((bits >> 8) & 2047u)], 1u);
            }
            __syncthreads();
        }
        unsigned part = hists[2 * tid] + hists[2 * tid + 1]
                      + hists[2048 + 2 * tid] + hists[2048 + 2 * tid + 1];
        unsigned s = part;
#pragma unroll
        for (int d = 1; d < 64; d <<= 1) {
            unsigned v = __shfl_down(s, d);
            if (lane < 64 - d) s += v;
        }
        if (lane == 0) wtot[wid] = s;
        __syncthreads();
        unsigned S = s;
        for (int w = wid + 1; w < 16; ++w) S += wtot[w];
        unsigned Ktgt = (pass == 0) ? TOPK : K2;
        if (S >= Ktgt && S - part < Ktgt) {     // unique crossing thread
            unsigned acc = S - part;
            for (int i = 1; i >= 0; --i) {
                int bin = 2 * tid + i;
                unsigned h = hists[bin] + hists[2048 + bin];
                acc += h;
                if (acc >= Ktgt) { misc[2] = (unsigned)bin; misc[3] = acc - h; break; }
            }
        }
        __syncthreads();
        if (pass == 0) { B = misc[2]; K2 = Ktgt - misc[3]; }
        else           { B2 = misc[2]; }
    }
    unsigned T = (B << 19) | (B2 << 8);

    // ---- collect {bits >= T} into LDS key list ----
    for (int i = tid; i < NPC; i += 1024) {
        unsigned bits = __float_as_uint(sconf[i]);
        if (bits >= T) {
            unsigned pos = atomicAdd(&misc[0], 1u);
            if (pos < MCAP)
                sk[pos] = ((unsigned long long)bits << 32) | (unsigned)(~i);
        }
    }
    __syncthreads();
    unsigned cn = misc[0];
    int n = (cn < (unsigned)MCAP) ? (int)cn : MCAP;

    // ---- recompute boxes for collected candidates (bit-identical arithmetic) ----
    for (int i = tid; i < n; i += 1024) {
        int idx = (int)(~(unsigned)sk[i]);
        const float* row = xg + (long)idx * 85;
        float v0 = row[0], v1 = row[1], v2 = row[2], v3 = row[3];
        int bc = (int)gbc[idx];
        int a   = idx / HW;
        int rem = idx - a * HW;
        int gy  = rem / NX;
        int gx  = rem - gy * NX;

        float cx = sigm(v0) * 2.0f + ((float)gx - 0.5f);
        float cy = sigm(v1) * 2.0f + ((float)gy - 0.5f);
        float tw = sigm(v2) * 2.0f, th = sigm(v3) * 2.0f;
        float w = (tw * tw) * anch[a * 2 + 0];
        float h = (th * th) * anch[a * 2 + 1];
        float x1 = cx - w / 2.0f, y1 = cy - h / 2.0f;
        float x2 = cx + w / 2.0f, y2 = cy + h / 2.0f;
        float offc = (float)bc * MAX_WH;
        sbox[i][0] = x1 + offc; sbox[i][1] = y1 + offc;
        sbox[i][2] = x2 + offc; sbox[i][3] = y2 + offc;
    }
    __syncthreads();

    // ---- wave-0 register-resident selection-sort NMS (no block barriers) ----
    if (tid < 64) {
        unsigned long long kreg[8];
#pragma unroll
        for (int j = 0; j < 8; ++j) {
            int s = tid + 64 * j;
            kreg[j] = (s < n) ? sk[s] : 0ULL;
        }
        float ex1 = 0.f, ey1 = 0.f, ex2 = 0.f, ey2 = 0.f;  // lane t holds selected box t
        int k = 0;
        while (k < MAX_DET) {
            unsigned long long mk = kreg[0]; int ms = tid;
#pragma unroll
            for (int j = 1; j < 8; ++j)
                if (kreg[j] > mk) { mk = kreg[j]; ms = tid + 64 * j; }
#pragma unroll
            for (int off = 32; off; off >>= 1) {
                unsigned long long ok = __shfl_xor(mk, off);
                int os = __shfl_xor(ms, off);
                if (ok > mk) { mk = ok; ms = os; }
            }
            if (mk == 0ULL) break;          // exhausted
#pragma unroll
            for (int j = 0; j < 8; ++j)
                if (ms == tid + 64 * j) kreg[j] = 0ULL;

            float cx1 = sbox[ms][0], cy1 = sbox[ms][1];
            float cx2 = sbox[ms][2], cy2 = sbox[ms][3];
            bool rej = false;
            if (tid < k) {
                float ltx = fmaxf(ex1, cx1), lty = fmaxf(ey1, cy1);
                float rbx = fminf(ex2, cx2), rby = fminf(ey2, cy2);
                float ww = fmaxf(rbx - ltx, 0.0f), hh = fmaxf(rby - lty, 0.0f);
                float inter = ww * hh;
                float area1 = (ex2 - ex1) * (ey2 - ey1);
                float area2 = (cx2 - cx1) * (cy2 - cy1);
                float iou = inter / (area1 + area2 - inter);
                rej = iou > IOU_THRES;
            }
            rej = __any(rej);
            if (!rej) {
                if (tid == k) { ex1 = cx1; ey1 = cy1; ex2 = cx2; ey2 = cy2; }
                if (tid == 0) { selIdx[k] = (int)(~(unsigned)mk); selValid[k] = 1; }
                ++k;
            }
        }
    }
    __syncthreads();

    // ---- fused gather: parallel over 25*C output elements ----
    const float* fb = feat + (long)b * C * HW;
    long obase = outOff + (long)b * MAX_DET * C;
    for (int e = tid; e < MAX_DET * C; e += 1024) {
        int k2 = e / C, c = e - k2 * C;
        float val = 0.0f;
        if (selValid[k2]) {
            int idx = selIdx[k2];
            int rem = idx % HW;
            val = fb[(long)c * HW + rem];   // rem = gy*NX + gx
        }
        out[obase + e] = val;
    }
}

__global__ __launch_bounds__(1024) void select_nms_gather_kernel(
    const float* __restrict__ confW, const unsigned short* __restrict__ bcW,
    const float* __restrict__ anch, float* __restrict__ out,
    LvlParams p0, LvlParams p1, LvlParams p2)
{
    __shared__ float sconf[19200];
    __shared__ unsigned long long sk[MCAP];
    __shared__ unsigned hists[4096];
    __shared__ float sbox[MCAP][4];
    __shared__ int   selIdx[MAX_DET];
    __shared__ int   selValid[MAX_DET];
    __shared__ unsigned wtot[16];
    __shared__ unsigned misc[4];

    int grp = blockIdx.x;
    int lvl = grp >> 4, b = grp & 15;
    if (lvl == 0) {
        long base = p0.candOff + (long)b * 19200;
        run_group<80, 80>(confW + base, bcW + base, p0.x + base * 85, anch + 0,
                          p0.feat, p0.C, p0.outOff, b,
                          sconf, sk, hists, sbox, selIdx, selValid, wtot, misc, out);
    } else if (lvl == 1) {
        long base = p1.candOff + (long)b * 4800;
        run_group<40, 40>(confW + base, bcW + base, p1.x + (long)b * 4800 * 85, anch + 6,
                          p1.feat, p1.C, p1.outOff, b,
                          sconf, sk, hists, sbox, selIdx, selValid, wtot, misc, out);
    } else {
        long base = p2.candOff + (long)b * 1200;
        run_group<20, 20>(confW + base, bcW + base, p2.x + (long)b * 1200 * 85, anch + 12,
                          p2.feat, p2.C, p2.outOff, b,
                          sconf, sk, hists, sbox, selIdx, selValid, wtot, misc, out);
    }
}

extern "C" void kernel_launch(void* const* d_in, const int* in_sizes, int n_in,
                              void* d_out, int out_size, void* d_ws, size_t ws_size,
                              hipStream_t stream)
{
    const float* xs[3] = {nullptr, nullptr, nullptr};
    const float* fs[3] = {nullptr, nullptr, nullptr};
    const float* anch  = nullptr;
    for (int i = 0; i < n_in; ++i) {
        const float* p = (const float*)d_in[i];
        switch (in_sizes[i]) {
            case 26112000: xs[0] = p; break;
            case 6528000:  xs[1] = p; break;
            case 1632000:  xs[2] = p; break;
            case 13107200: fs[0] = p; break;
            case 6553600:  fs[1] = p; break;
            case 3276800:  fs[2] = p; break;
            case 18:       anch  = p; break;
        }
    }

    char* wsb = (char*)d_ws;
    float*          confW = (float*)wsb;                       // 403200 f32
    unsigned short* bcW   = (unsigned short*)(wsb + 1612800L); // 403200 u16

    decode_all_kernel<<<6300, 256, 0, stream>>>(xs[0], xs[1], xs[2], confW, bcW);

    LvlParams P0{fs[0], xs[0], 0L,      0L,      128};
    LvlParams P1{fs[1], xs[1], 307200L, 51200L,  256};
    LvlParams P2{fs[2], xs[2], 384000L, 153600L, 512};

    select_nms_gather_kernel<<<48, 1024, 0, stream>>>(confW, bcW, anch, (float*)d_out, P0, P1, P2);
}